// Round 1
// baseline (1052.228 us; speedup 1.0000x reference)
//
#include <hip/hip_runtime.h>
#include <math.h>

// ---------------------------------------------------------------------------
// SelfAttn2d: out = x + gamma * (V @ softmax(Q K^T / sqrt(32))^T)
// with spectrally-normalized projection weights.
// B=4, C=256, H=W=64, N=4096, D=32.
// fp32 baseline round: correctness first, flash-style (no attn materialization).
// ---------------------------------------------------------------------------

#define NPOS 4096
#define CCH  256
#define DQK  32
#define MT   64
#define NT   32

// ws layout (floats)
// [0..7]  scalars: 0=invsig_q 1=invsig_k 2=invsig_v
// [8..15] trace slots for wv squaring chain
// [64 ..]               Gv   (256x256)
// [64+65536 ..]         B1   (256x256)
// [64+2*65536 ..]       B2   (256x256)
// [64+3*65536 ..]       qkv  (4 x 320 x 4096)

// ---------------------------------------------------------------------------
// sigma for wq (block 0) and wk (block 1): Gram 32x32 in LDS, 8 in-LDS
// squarings with trace normalization, 4 power iters, Rayleigh vs original G.
// ---------------------------------------------------------------------------
__global__ __launch_bounds__(256) void sigma_qk(const float* __restrict__ wq,
                                                const float* __restrict__ wk,
                                                float* __restrict__ scal) {
    const float* w = (blockIdx.x == 0) ? wq : wk;
    __shared__ float Ws[32][257];
    __shared__ float G[32][33], A[32][33], Bt[32][33];
    __shared__ float xv[32], yv[32];
    __shared__ float sred;
    int t = threadIdx.x;

    // stage w (32x256) into LDS, coalesced
    for (int i = 0; i < 32; i++) {
        int idx = t + 256 * i;           // 0..8191
        Ws[idx >> 8][idx & 255] = w[idx];
    }
    __syncthreads();

    // Gram G = w w^T  (1024 entries, 4 per thread)
    for (int i = 0; i < 4; i++) {
        int id = t + 256 * i;
        int r = id >> 5, cc = id & 31;
        float s = 0.f;
        for (int c = 0; c < 256; c++) s += Ws[r][c] * Ws[cc][c];
        G[r][cc] = s;
        A[r][cc] = s;
    }
    __syncthreads();

    // 8 squarings with trace normalization: A <- (A/tr)^2
    for (int sq = 0; sq < 8; sq++) {
        if (t == 0) {
            float tr = 0.f;
            for (int i = 0; i < 32; i++) tr += A[i][i];
            sred = 1.0f / tr;
        }
        __syncthreads();
        float invt = sred;
        for (int i = 0; i < 4; i++) {
            int id = t + 256 * i;
            int r = id >> 5, cc = id & 31;
            float s = 0.f;
            #pragma unroll
            for (int k2 = 0; k2 < 32; k2++) s += A[r][k2] * A[cc][k2];  // A symmetric
            Bt[r][cc] = s * invt * invt;
        }
        __syncthreads();
        for (int i = 0; i < 4; i++) {
            int id = t + 256 * i;
            A[id >> 5][id & 31] = Bt[id >> 5][id & 31];
        }
        __syncthreads();
    }

    // 4 power iterations with M = A
    if (t < 32) xv[t] = 1.0f + 0.01f * t;
    __syncthreads();
    for (int it = 0; it < 4; it++) {
        if (t < 32) {
            float y = 0.f;
            #pragma unroll
            for (int j = 0; j < 32; j++) y += A[t][j] * xv[j];
            yv[t] = y;
        }
        __syncthreads();
        if (t < 32) {
            float ss = 0.f;
            #pragma unroll
            for (int j = 0; j < 32; j++) ss += yv[j] * yv[j];
            xv[t] = yv[t] * rsqrtf(ss);
        }
        __syncthreads();
    }
    // Rayleigh with original G: lambda = x^T G x (||x||=1); invsigma = 1/sqrt(lambda)
    if (t == 0) {
        float lam = 0.f;
        for (int i = 0; i < 32; i++) {
            float y = 0.f;
            for (int j = 0; j < 32; j++) y += G[i][j] * xv[j];
            lam += xv[i] * y;
        }
        scal[blockIdx.x] = rsqrtf(lam);
    }
}

// ---------------------------------------------------------------------------
// Gv = wv wv^T (256x256). 64 blocks x 4 rows. Also atomicAdd diagonal -> tr0.
// ---------------------------------------------------------------------------
__global__ __launch_bounds__(256) void gram_v(const float* __restrict__ wv,
                                              float* __restrict__ Gv,
                                              float* __restrict__ tr) {
    int i0 = blockIdx.x * 4, j = threadIdx.x;
    __shared__ float rowi[4][256];
    for (int r = 0; r < 4; r++) rowi[r][j] = wv[(i0 + r) * 256 + j];
    __syncthreads();
    float s[4] = {0.f, 0.f, 0.f, 0.f};
    for (int c = 0; c < 256; c++) {
        float a = wv[j * 256 + c];
        #pragma unroll
        for (int r = 0; r < 4; r++) s[r] += rowi[r][c] * a;
    }
    for (int r = 0; r < 4; r++) {
        Gv[(i0 + r) * 256 + j] = s[r];
        if (j == i0 + r) atomicAdd(tr, s[r]);
    }
}

// ---------------------------------------------------------------------------
// C = (A / *tin)^2 for symmetric PSD A (256x256); diag of C atomicAdd -> tout.
// ---------------------------------------------------------------------------
__global__ __launch_bounds__(256) void sq_k(const float* __restrict__ A,
                                            float* __restrict__ C,
                                            const float* __restrict__ tin,
                                            float* __restrict__ tout) {
    float invt = 1.0f / (*tin);
    int i0 = blockIdx.x * 4, j = threadIdx.x;
    __shared__ float rowi[4][256];
    for (int r = 0; r < 4; r++) rowi[r][j] = A[(i0 + r) * 256 + j];
    __syncthreads();
    float s[4] = {0.f, 0.f, 0.f, 0.f};
    for (int c = 0; c < 256; c++) {
        float a = A[j * 256 + c];  // A symmetric: row j == col j
        #pragma unroll
        for (int r = 0; r < 4; r++) s[r] += rowi[r][c] * a;
    }
    for (int r = 0; r < 4; r++) {
        float val = s[r] * invt * invt;
        C[(i0 + r) * 256 + j] = val;
        if (j == i0 + r) atomicAdd(tout, val);
    }
}

// ---------------------------------------------------------------------------
// power iterations with M (=Gv^(64), normalized), Rayleigh vs Gv -> invsig_v
// ---------------------------------------------------------------------------
__global__ __launch_bounds__(256) void power_v(const float* __restrict__ M,
                                               const float* __restrict__ G,
                                               float* __restrict__ scal) {
    __shared__ float xv[256], red[256];
    __shared__ float nrm;
    int t = threadIdx.x;
    xv[t] = 1.0f + 0.01f * t;
    __syncthreads();
    for (int it = 0; it < 8; it++) {
        float y = 0.f;
        for (int j = 0; j < 256; j++) y += M[t * 256 + j] * xv[j];
        red[t] = y * y;
        __syncthreads();
        for (int s2 = 128; s2 > 0; s2 >>= 1) {
            if (t < s2) red[t] += red[t + s2];
            __syncthreads();
        }
        if (t == 0) nrm = rsqrtf(red[0]);
        __syncthreads();
        xv[t] = y * nrm;
        __syncthreads();
    }
    float y2 = 0.f;
    for (int j = 0; j < 256; j++) y2 += G[t * 256 + j] * xv[j];
    red[t] = y2 * xv[t];
    __syncthreads();
    for (int s2 = 128; s2 > 0; s2 >>= 1) {
        if (t < s2) red[t] += red[t + s2];
        __syncthreads();
    }
    if (t == 0) scal[2] = rsqrtf(red[0]);
}

// ---------------------------------------------------------------------------
// qkv[b][row][n], rows 0..31 = q (raw), 32..63 = k (raw), 64..319 = v*invsig_v
// grid (16 n-tiles, 20 row-tiles, 4 b), block 256 (one n each, 16 rows).
// Weight reads are block-uniform -> scalar loads.
// ---------------------------------------------------------------------------
__global__ __launch_bounds__(256) void qkv_kernel(const float* __restrict__ x,
                                                  const float* __restrict__ wq,
                                                  const float* __restrict__ wk,
                                                  const float* __restrict__ wv,
                                                  const float* __restrict__ scal,
                                                  float* __restrict__ qkv) {
    int n = blockIdx.x * 256 + threadIdx.x;
    int row0 = blockIdx.y * 16;
    int b = blockIdx.z;
    const float* xb = x + ((size_t)b << 20);  // b*256*4096
    const float* wbase;
    float scale = 1.0f;
    if (row0 < 32)      { wbase = wq + row0 * 256; }
    else if (row0 < 64) { wbase = wk + (row0 - 32) * 256; }
    else                { wbase = wv + (row0 - 64) * 256; scale = scal[2]; }

    float acc[16];
    #pragma unroll
    for (int r = 0; r < 16; r++) acc[r] = 0.f;
    for (int c = 0; c < 256; c++) {
        float xvv = xb[c * NPOS + n];
        #pragma unroll
        for (int r = 0; r < 16; r++) acc[r] += wbase[r * 256 + c] * xvv;
    }
    float* q0 = qkv + ((size_t)b * 320 + row0) * NPOS + n;
    #pragma unroll
    for (int r = 0; r < 16; r++) q0[(size_t)r * NPOS] = acc[r] * scale;
}

// ---------------------------------------------------------------------------
// Fused attention. Per block: batch b, 64-query tile. No max-subtraction
// (spectral norm bounds logits << fp32 exp overflow). Accumulates
// out_unnorm[e,m] = sum_n exp(s)*v[e,n] and L[m] = sum_n exp(s); divides at end.
// block = 512 threads. Thread PV tile: 4 m (stride 16) x 8 e (stride 32).
// ---------------------------------------------------------------------------
__global__ __launch_bounds__(512) void attn_kernel(const float* __restrict__ x,
                                                   const float* __restrict__ qkv,
                                                   const float* __restrict__ scal,
                                                   const float* __restrict__ gam,
                                                   float* __restrict__ out) {
    int b = blockIdx.y;
    int m0 = blockIdx.x * MT;
    const float* qb = qkv + (size_t)b * 320 * NPOS;
    const float* kb = qb + 32 * NPOS;
    const float* vb = qb + 64 * NPOS;

    __shared__ float Qs[32][MT];        // [d][m]
    __shared__ float Ks[32][NT];        // [d][n]
    __shared__ float Vs[256][NT + 1];   // [e][n] padded
    __shared__ float Ps[MT][NT + 1];    // [m][n] padded
    __shared__ float Ls[MT];

    int t = threadIdx.x;
    float qkscale = scal[0] * scal[1] * 0.17677669529663687f;  // 1/sqrt(32)

    #pragma unroll
    for (int i = 0; i < 4; i++) {
        int id = t + 512 * i;  // 0..2047
        Qs[id >> 6][id & 63] = qb[(size_t)(id >> 6) * NPOS + m0 + (id & 63)];
    }
    if (t < MT) Ls[t] = 0.f;

    float acc[32];
    #pragma unroll
    for (int i = 0; i < 32; i++) acc[i] = 0.f;

    int ns = t & 31, msb = (t >> 5) << 2;  // S-phase: 4 m's, one n
    int eg = t & 31, mq = t >> 5;          // PV: m = mq+16i, e = eg+32j

    for (int n0 = 0; n0 < NPOS; n0 += NT) {
        __syncthreads();
        #pragma unroll
        for (int i = 0; i < 2; i++) {
            int id = t + 512 * i;  // 0..1023
            Ks[id >> 5][id & 31] = kb[(size_t)(id >> 5) * NPOS + n0 + (id & 31)];
        }
        #pragma unroll
        for (int i = 0; i < 16; i++) {
            int e = (t >> 5) + 16 * i;
            Vs[e][t & 31] = vb[(size_t)e * NPOS + n0 + (t & 31)];
        }
        __syncthreads();

        // S = Q^T K, P = exp(S * qkscale)
        float sv[4] = {0.f, 0.f, 0.f, 0.f};
        #pragma unroll
        for (int d = 0; d < 32; d++) {
            float kk = Ks[d][ns];
            #pragma unroll
            for (int i = 0; i < 4; i++) sv[i] += Qs[d][msb + i] * kk;
        }
        #pragma unroll
        for (int i = 0; i < 4; i++) Ps[msb + i][ns] = __expf(sv[i] * qkscale);
        __syncthreads();

        if (t < MT) {
            float l = 0.f;
            #pragma unroll
            for (int n = 0; n < NT; n++) l += Ps[t][n];
            Ls[t] += l;
        }
        #pragma unroll
        for (int n = 0; n < NT; n++) {
            float pr[4], vr[8];
            #pragma unroll
            for (int i = 0; i < 4; i++) pr[i] = Ps[mq + 16 * i][n];
            #pragma unroll
            for (int j = 0; j < 8; j++) vr[j] = Vs[eg + 32 * j][n];
            #pragma unroll
            for (int i = 0; i < 4; i++)
                #pragma unroll
                for (int j = 0; j < 8; j++) acc[i * 8 + j] += pr[i] * vr[j];
        }
    }
    __syncthreads();

    // epilogue: out = x + gamma * acc / L, staged via LDS (2 chunks of 128 e)
    float g = gam[0];
    const float* xb = x + ((size_t)b << 20);
    float* ob = out + ((size_t)b << 20);
    float invL[4];
    #pragma unroll
    for (int i = 0; i < 4; i++) invL[i] = g / Ls[mq + 16 * i];
    float* Os = &Vs[0][0];  // reuse as [128][65] (8320 <= 8448 floats)

    for (int chunk = 0; chunk < 2; chunk++) {
        __syncthreads();
        #pragma unroll
        for (int i = 0; i < 4; i++)
            #pragma unroll
            for (int j = 0; j < 4; j++) {
                int jj = j + 4 * chunk;
                int e_loc = eg + 32 * j;  // 0..127
                Os[e_loc * 65 + (mq + 16 * i)] = acc[i * 8 + jj] * invL[i];
            }
        __syncthreads();
        #pragma unroll
        for (int ii = 0; ii < 16; ii++) {
            int m = t & 63;
            int e2 = (t >> 6) + 8 * ii;  // 0..127
            int e = e2 + 128 * chunk;
            size_t idx = (size_t)e * NPOS + m0 + m;
            ob[idx] = xb[idx] + Os[e2 * 65 + m];
        }
    }
}

// ---------------------------------------------------------------------------
extern "C" void kernel_launch(void* const* d_in, const int* in_sizes, int n_in,
                              void* d_out, int out_size, void* d_ws, size_t ws_size,
                              hipStream_t stream) {
    const float* x     = (const float*)d_in[0];
    const float* wq    = (const float*)d_in[1];
    const float* wk    = (const float*)d_in[2];
    const float* wv    = (const float*)d_in[3];
    const float* gamma = (const float*)d_in[4];
    float* out = (float*)d_out;
    float* ws  = (float*)d_ws;

    float* scal = ws;          // [0..7]
    float* tr   = ws + 8;      // [8..15]
    float* Gv   = ws + 64;
    float* B1   = Gv + 65536;
    float* B2   = B1 + 65536;
    float* qkvp = B2 + 65536;  // 4*320*4096 floats

    hipMemsetAsync(ws, 0, 64 * sizeof(float), stream);

    sigma_qk<<<2, 256, 0, stream>>>(wq, wk, scal);

    gram_v<<<64, 256, 0, stream>>>(wv, Gv, tr + 0);
    sq_k<<<64, 256, 0, stream>>>(Gv, B1, tr + 0, tr + 1);
    sq_k<<<64, 256, 0, stream>>>(B1, B2, tr + 1, tr + 2);
    sq_k<<<64, 256, 0, stream>>>(B2, B1, tr + 2, tr + 3);
    sq_k<<<64, 256, 0, stream>>>(B1, B2, tr + 3, tr + 4);
    sq_k<<<64, 256, 0, stream>>>(B2, B1, tr + 4, tr + 5);
    sq_k<<<64, 256, 0, stream>>>(B1, B2, tr + 5, tr + 6);
    power_v<<<1, 256, 0, stream>>>(B2, Gv, scal);

    qkv_kernel<<<dim3(16, 20, 4), 256, 0, stream>>>(x, wq, wk, wv, scal, qkvp);
    attn_kernel<<<dim3(64, 4), 512, 0, stream>>>(x, qkvp, scal, gamma, out);
}

// Round 2
// 564.251 us; speedup vs baseline: 1.8648x; 1.8648x over previous
//
#include <hip/hip_runtime.h>
#include <hip/hip_bf16.h>
#include <math.h>

// ---------------------------------------------------------------------------
// SelfAttn2d: out = x + gamma * (V @ softmax(Q K^T / sqrt(32))^T)
// B=4, C=256, N=4096, D=32.  Round 2: MFMA bf16 flash attention.
// ---------------------------------------------------------------------------

#define NPOS 4096

typedef __bf16 bf16x8 __attribute__((ext_vector_type(8)));
typedef float  f32x16 __attribute__((ext_vector_type(16)));

static __device__ inline unsigned int pk2(float a, float b) {
    union { __hip_bfloat16 h[2]; unsigned int u; } x;
    x.h[0] = __float2bfloat16(a);
    x.h[1] = __float2bfloat16(b);
    return x.u;
}

// ---------------------------------------------------------------------------
// sigma for wq (block 0) and wk (block 1): Gram 32x32 in LDS, 8 squarings
// with trace normalization, 4 power iters, Rayleigh vs original G.
// ---------------------------------------------------------------------------
__global__ __launch_bounds__(256) void sigma_qk(const float* __restrict__ wq,
                                                const float* __restrict__ wk,
                                                float* __restrict__ scal) {
    const float* w = (blockIdx.x == 0) ? wq : wk;
    __shared__ float Ws[32][257];
    __shared__ float G[32][33], A[32][33], Bt[32][33];
    __shared__ float xv[32], yv[32];
    __shared__ float sred;
    int t = threadIdx.x;

    for (int i = 0; i < 32; i++) {
        int idx = t + 256 * i;
        Ws[idx >> 8][idx & 255] = w[idx];
    }
    __syncthreads();

    for (int i = 0; i < 4; i++) {
        int id = t + 256 * i;
        int r = id >> 5, cc = id & 31;
        float s = 0.f;
        for (int c = 0; c < 256; c++) s += Ws[r][c] * Ws[cc][c];
        G[r][cc] = s;
        A[r][cc] = s;
    }
    __syncthreads();

    for (int sq = 0; sq < 8; sq++) {
        if (t == 0) {
            float tr = 0.f;
            for (int i = 0; i < 32; i++) tr += A[i][i];
            sred = 1.0f / tr;
        }
        __syncthreads();
        float invt = sred;
        for (int i = 0; i < 4; i++) {
            int id = t + 256 * i;
            int r = id >> 5, cc = id & 31;
            float s = 0.f;
            #pragma unroll
            for (int k2 = 0; k2 < 32; k2++) s += A[r][k2] * A[cc][k2];
            Bt[r][cc] = s * invt * invt;
        }
        __syncthreads();
        for (int i = 0; i < 4; i++) {
            int id = t + 256 * i;
            A[id >> 5][id & 31] = Bt[id >> 5][id & 31];
        }
        __syncthreads();
    }

    if (t < 32) xv[t] = 1.0f + 0.01f * t;
    __syncthreads();
    for (int it = 0; it < 4; it++) {
        if (t < 32) {
            float y = 0.f;
            #pragma unroll
            for (int j = 0; j < 32; j++) y += A[t][j] * xv[j];
            yv[t] = y;
        }
        __syncthreads();
        if (t < 32) {
            float ss = 0.f;
            #pragma unroll
            for (int j = 0; j < 32; j++) ss += yv[j] * yv[j];
            xv[t] = yv[t] * rsqrtf(ss);
        }
        __syncthreads();
    }
    if (t == 0) {
        float lam = 0.f;
        for (int i = 0; i < 32; i++) {
            float y = 0.f;
            for (int j = 0; j < 32; j++) y += G[i][j] * xv[j];
            lam += xv[i] * y;
        }
        scal[blockIdx.x] = rsqrtf(lam);
    }
}

// ---------------------------------------------------------------------------
__global__ __launch_bounds__(256) void gram_v(const float* __restrict__ wv,
                                              float* __restrict__ Gv,
                                              float* __restrict__ tr) {
    int i0 = blockIdx.x * 4, j = threadIdx.x;
    __shared__ float rowi[4][256];
    for (int r = 0; r < 4; r++) rowi[r][j] = wv[(i0 + r) * 256 + j];
    __syncthreads();
    float s[4] = {0.f, 0.f, 0.f, 0.f};
    for (int c = 0; c < 256; c++) {
        float a = wv[j * 256 + c];
        #pragma unroll
        for (int r = 0; r < 4; r++) s[r] += rowi[r][c] * a;
    }
    for (int r = 0; r < 4; r++) {
        Gv[(i0 + r) * 256 + j] = s[r];
        if (j == i0 + r) atomicAdd(tr, s[r]);
    }
}

__global__ __launch_bounds__(256) void sq_k(const float* __restrict__ A,
                                            float* __restrict__ C,
                                            const float* __restrict__ tin,
                                            float* __restrict__ tout) {
    float invt = 1.0f / (*tin);
    int i0 = blockIdx.x * 4, j = threadIdx.x;
    __shared__ float rowi[4][256];
    for (int r = 0; r < 4; r++) rowi[r][j] = A[(i0 + r) * 256 + j];
    __syncthreads();
    float s[4] = {0.f, 0.f, 0.f, 0.f};
    for (int c = 0; c < 256; c++) {
        float a = A[j * 256 + c];
        #pragma unroll
        for (int r = 0; r < 4; r++) s[r] += rowi[r][c] * a;
    }
    for (int r = 0; r < 4; r++) {
        float val = s[r] * invt * invt;
        C[(i0 + r) * 256 + j] = val;
        if (j == i0 + r) atomicAdd(tout, val);
    }
}

__global__ __launch_bounds__(256) void power_v(const float* __restrict__ M,
                                               const float* __restrict__ G,
                                               float* __restrict__ scal) {
    __shared__ float xv[256], red[256];
    __shared__ float nrm;
    int t = threadIdx.x;
    xv[t] = 1.0f + 0.01f * t;
    __syncthreads();
    for (int it = 0; it < 8; it++) {
        float y = 0.f;
        for (int j = 0; j < 256; j++) y += M[t * 256 + j] * xv[j];
        red[t] = y * y;
        __syncthreads();
        for (int s2 = 128; s2 > 0; s2 >>= 1) {
            if (t < s2) red[t] += red[t + s2];
            __syncthreads();
        }
        if (t == 0) nrm = rsqrtf(red[0]);
        __syncthreads();
        xv[t] = y * nrm;
        __syncthreads();
    }
    float y2 = 0.f;
    for (int j = 0; j < 256; j++) y2 += G[t * 256 + j] * xv[j];
    red[t] = y2 * xv[t];
    __syncthreads();
    for (int s2 = 128; s2 > 0; s2 >>= 1) {
        if (t < s2) red[t] += red[t + s2];
        __syncthreads();
    }
    if (t == 0) scal[2] = rsqrtf(red[0]);
}

// ---------------------------------------------------------------------------
// qk_proj: qT[b][n][32], kT[b][n][32] bf16 (RAW: no sigma; folded into attn).
// One thread per n; weights via scalar loads; 16B packed row stores.
// ---------------------------------------------------------------------------
__global__ __launch_bounds__(128) void qk_proj(const float* __restrict__ x,
                                               const float* __restrict__ wq,
                                               const float* __restrict__ wk,
                                               __hip_bfloat16* __restrict__ qT,
                                               __hip_bfloat16* __restrict__ kT) {
    int n = blockIdx.x * 128 + threadIdx.x;
    int b = blockIdx.y;
    const float* xb = x + ((size_t)b << 20);
    float aq[32], ak[32];
    #pragma unroll
    for (int d = 0; d < 32; d++) { aq[d] = 0.f; ak[d] = 0.f; }
    for (int c = 0; c < 256; c++) {
        float xv = xb[(size_t)c * NPOS + n];
        #pragma unroll
        for (int d = 0; d < 32; d++) {
            aq[d] += wq[d * 256 + c] * xv;
            ak[d] += wk[d * 256 + c] * xv;
        }
    }
    size_t ro = ((size_t)b * NPOS + n) * 32;
    uint4* qp = (uint4*)(qT + ro);
    uint4* kp = (uint4*)(kT + ro);
    #pragma unroll
    for (int g = 0; g < 4; g++) {
        uint4 uq, uk;
        uq.x = pk2(aq[8 * g + 0], aq[8 * g + 1]); uq.y = pk2(aq[8 * g + 2], aq[8 * g + 3]);
        uq.z = pk2(aq[8 * g + 4], aq[8 * g + 5]); uq.w = pk2(aq[8 * g + 6], aq[8 * g + 7]);
        uk.x = pk2(ak[8 * g + 0], ak[8 * g + 1]); uk.y = pk2(ak[8 * g + 2], ak[8 * g + 3]);
        uk.z = pk2(ak[8 * g + 4], ak[8 * g + 5]); uk.w = pk2(ak[8 * g + 6], ak[8 * g + 7]);
        qp[g] = uq;
        kp[g] = uk;
    }
}

// ---------------------------------------------------------------------------
// v_proj: v[b][e][n] bf16 (RAW wv @ x; sigma_v folded into attn epilogue).
// ---------------------------------------------------------------------------
__global__ __launch_bounds__(256) void v_proj(const float* __restrict__ x,
                                              const float* __restrict__ wv,
                                              __hip_bfloat16* __restrict__ v) {
    int n = blockIdx.x * 256 + threadIdx.x;
    int e0 = blockIdx.y * 16;
    int b = blockIdx.z;
    const float* xb = x + ((size_t)b << 20);
    float acc[16];
    #pragma unroll
    for (int r = 0; r < 16; r++) acc[r] = 0.f;
    for (int c = 0; c < 256; c++) {
        float xv = xb[(size_t)c * NPOS + n];
        #pragma unroll
        for (int r = 0; r < 16; r++) acc[r] += wv[(e0 + r) * 256 + c] * xv;
    }
    #pragma unroll
    for (int r = 0; r < 16; r++)
        v[((size_t)b * 256 + e0 + r) * NPOS + n] = __float2bfloat16(acc[r]);
}

// ---------------------------------------------------------------------------
// MFMA flash attention. Block: 256 thr (4 waves), Mq=64 q-tile, Nk step 64.
// Sphase (wave w -> S^T quadrant [ntile=w&1][mtile=w>>1]):
//   S^T[n][m] = sum_d kT[n][d] qT[m][d] via 2x mfma_32x32x16 (A=K, B=Q).
//   C-layout: col(lane&31)=m, row(reg pattern)=n -> exp+pack -> ds_write_b64,
//   L[m] accumulates per-lane (all regs share m).
// PV (wave w -> e-range w*64..+63, all 64 m):
//   D[e][m] += v-frag (global direct) x P-frag (LDS b128), 16 mfma/step.
// P LDS stride 72 bf16 = 144B = 9 x 16B -> conflict-free b128 reads.
// No max-subtraction: spectral norm bounds logits ~ +-1 << fp32 exp range.
// ---------------------------------------------------------------------------
__global__ __launch_bounds__(256) void attn_mfma(const float* __restrict__ x,
                                                 const __hip_bfloat16* __restrict__ qT,
                                                 const __hip_bfloat16* __restrict__ kT,
                                                 const __hip_bfloat16* __restrict__ v,
                                                 const float* __restrict__ scal,
                                                 const float* __restrict__ gam,
                                                 float* __restrict__ out) {
    __shared__ __hip_bfloat16 Plds[64 * 72];
    __shared__ float Lpart[4][32];

    int t = threadIdx.x;
    int wave = t >> 6, lane = t & 63;
    int lo = lane & 31, hi = lane >> 5;

    // XCD swizzle: batch b pinned to XCDs {2b, 2b+1} (heuristic, perf-only)
    int blk = blockIdx.x;
    int x8 = blk & 7;
    int b = x8 >> 1;
    int m0 = (((x8 & 1) << 5) + (blk >> 3)) << 6;

    const __hip_bfloat16* qTb = qT + ((size_t)b << 17);  // 4096*32
    const __hip_bfloat16* kTb = kT + ((size_t)b << 17);
    const __hip_bfloat16* vb  = v  + ((size_t)b << 20);  // 256*4096

    int mtile_s = wave >> 1, ntile_s = wave & 1;
    int e0w = wave << 6;
    float qkscale = scal[0] * scal[1] * 0.17677669529663687f;  // sig_q sig_k / sqrt(32)

    // persistent Q B-frags for this wave's S m-tile
    bf16x8 qf0 = *(const bf16x8*)(qTb + ((size_t)(m0 + mtile_s * 32 + lo)) * 32 + 0  + hi * 8);
    bf16x8 qf1 = *(const bf16x8*)(qTb + ((size_t)(m0 + mtile_s * 32 + lo)) * 32 + 16 + hi * 8);

    f32x16 acc[2][2];
    #pragma unroll
    for (int et = 0; et < 2; et++)
        #pragma unroll
        for (int mt = 0; mt < 2; mt++)
            #pragma unroll
            for (int r = 0; r < 16; r++) acc[et][mt][r] = 0.f;
    float l_acc = 0.f;

    for (int n0 = 0; n0 < NPOS; n0 += 64) {
        // ---- S^T phase ----
        const __hip_bfloat16* krow = kTb + ((size_t)(n0 + ntile_s * 32 + lo)) * 32 + hi * 8;
        bf16x8 kf0 = *(const bf16x8*)(krow);
        bf16x8 kf1 = *(const bf16x8*)(krow + 16);
        f32x16 s;
        #pragma unroll
        for (int r = 0; r < 16; r++) s[r] = 0.f;
        s = __builtin_amdgcn_mfma_f32_32x32x16_bf16(kf0, qf0, s, 0, 0, 0);
        s = __builtin_amdgcn_mfma_f32_32x32x16_bf16(kf1, qf1, s, 0, 0, 0);

        __syncthreads();  // previous PV reads of Plds are done
        int mrow = mtile_s * 32 + lo;
        #pragma unroll
        for (int g = 0; g < 4; g++) {
            float p0 = __expf(s[4 * g + 0] * qkscale);
            float p1 = __expf(s[4 * g + 1] * qkscale);
            float p2 = __expf(s[4 * g + 2] * qkscale);
            float p3 = __expf(s[4 * g + 3] * qkscale);
            l_acc += (p0 + p1) + (p2 + p3);
            uint2 pk;
            pk.x = pk2(p0, p1);
            pk.y = pk2(p2, p3);
            int nloc = ntile_s * 32 + 8 * g + 4 * hi;   // n = nloc..nloc+3
            *(uint2*)(&Plds[mrow * 72 + nloc]) = pk;
        }
        __syncthreads();  // P tile ready

        // ---- PV phase ----
        #pragma unroll
        for (int kc = 0; kc < 4; kc++) {
            bf16x8 pf0 = *(const bf16x8*)(&Plds[(lo)      * 72 + kc * 16 + hi * 8]);
            bf16x8 pf1 = *(const bf16x8*)(&Plds[(32 + lo) * 72 + kc * 16 + hi * 8]);
            bf16x8 vf0 = *(const bf16x8*)(vb + (size_t)(e0w + lo)      * NPOS + n0 + kc * 16 + hi * 8);
            bf16x8 vf1 = *(const bf16x8*)(vb + (size_t)(e0w + 32 + lo) * NPOS + n0 + kc * 16 + hi * 8);
            acc[0][0] = __builtin_amdgcn_mfma_f32_32x32x16_bf16(vf0, pf0, acc[0][0], 0, 0, 0);
            acc[0][1] = __builtin_amdgcn_mfma_f32_32x32x16_bf16(vf0, pf1, acc[0][1], 0, 0, 0);
            acc[1][0] = __builtin_amdgcn_mfma_f32_32x32x16_bf16(vf1, pf0, acc[1][0], 0, 0, 0);
            acc[1][1] = __builtin_amdgcn_mfma_f32_32x32x16_bf16(vf1, pf1, acc[1][1], 0, 0, 0);
        }
    }

    // ---- L reduction: lane and lane^32 hold same m, different n halves ----
    float lsum = l_acc + __shfl_xor(l_acc, 32, 64);
    if (lane < 32) Lpart[wave][lane] = lsum;
    __syncthreads();

    // ---- epilogue: out = x + gamma*sig_v * acc / L ----
    float gs = gam[0] * scal[2];
    const float* xb = x + ((size_t)b << 20);
    float* ob = out + ((size_t)b << 20);
    #pragma unroll
    for (int mt = 0; mt < 2; mt++) {
        float L = Lpart[2 * mt][lo] + Lpart[2 * mt + 1][lo];
        float f = gs / L;
        int m = m0 + mt * 32 + lo;
        #pragma unroll
        for (int et = 0; et < 2; et++) {
            #pragma unroll
            for (int r = 0; r < 16; r++) {
                int e = e0w + et * 32 + (r & 3) + 8 * (r >> 2) + 4 * hi;
                size_t idx = (size_t)e * NPOS + m;
                ob[idx] = xb[idx] + f * acc[et][mt][r];
            }
        }
    }
}

// ---------------------------------------------------------------------------
extern "C" void kernel_launch(void* const* d_in, const int* in_sizes, int n_in,
                              void* d_out, int out_size, void* d_ws, size_t ws_size,
                              hipStream_t stream) {
    const float* x     = (const float*)d_in[0];
    const float* wq    = (const float*)d_in[1];
    const float* wk    = (const float*)d_in[2];
    const float* wv    = (const float*)d_in[3];
    const float* gamma = (const float*)d_in[4];
    float* out = (float*)d_out;

    char* wsb = (char*)d_ws;
    float* scal = (float*)wsb;                    // [0..7] scalars
    float* tr   = scal + 8;                       // [8..15] traces
    float* Gv   = (float*)(wsb + 256);            // 256KB
    float* B1   = Gv + 65536;
    float* B2   = B1 + 65536;
    __hip_bfloat16* qT = (__hip_bfloat16*)(wsb + 256 + 3 * 65536 * sizeof(float));
    __hip_bfloat16* kT = qT + (size_t)4 * NPOS * 32;
    __hip_bfloat16* vp = kT + (size_t)4 * NPOS * 32;   // 4*256*4096 bf16

    hipMemsetAsync(scal, 0, 64 * sizeof(float), stream);

    // projections (raw, sigma folded into attention)
    qk_proj<<<dim3(32, 4), 128, 0, stream>>>(x, wq, wk, qT, kT);
    v_proj<<<dim3(16, 16, 4), 256, 0, stream>>>(x, wv, vp);

    // spectral norms
    sigma_qk<<<2, 256, 0, stream>>>(wq, wk, scal);
    gram_v<<<64, 256, 0, stream>>>(wv, Gv, tr + 0);
    sq_k<<<64, 256, 0, stream>>>(Gv, B1, tr + 0, tr + 1);
    sq_k<<<64, 256, 0, stream>>>(B1, B2, tr + 1, tr + 2);
    sq_k<<<64, 256, 0, stream>>>(B2, B1, tr + 2, tr + 3);
    sq_k<<<64, 256, 0, stream>>>(B1, B2, tr + 3, tr + 4);
    sq_k<<<64, 256, 0, stream>>>(B2, B1, tr + 4, tr + 5);
    sq_k<<<64, 256, 0, stream>>>(B1, B2, tr + 5, tr + 6);
    power_v<<<1, 256, 0, stream>>>(B2, Gv, scal);

    attn_mfma<<<256, 256, 0, stream>>>(x, qT, kT, vp, scal, gamma, out);
}